// Round 4
// baseline (1049.425 us; speedup 1.0000x reference)
//
#include <hip/hip_runtime.h>
#include <hip/hip_bf16.h>
#include <stdint.h>

typedef __hip_bfloat16 bf16;
typedef __attribute__((ext_vector_type(8))) short frag8;     // 8 bf16 = 4 VGPRs
typedef __attribute__((ext_vector_type(4))) float floatx4;   // MFMA acc

#define B_WIN 512
#define L_TOK 196
#define C_DIM 384
#define NH    12
#define HD    32
#define QP    208   // 13*16 q-rows padded
#define KPAD  224   // 14*16 k padded (exactly 56 P-vals/lane = 7 PV chunks)
#define VSTR  236   // vT row stride: 472B. write: 2-way; read: free
// scale = hd^-0.5 * log2(e)  (exp2 softmax; base change folded into logits+bias)
#define QSCALE 0.2550348555f

#if defined(__has_builtin)
#if __has_builtin(__builtin_amdgcn_exp2f)
#define EXP2(x) __builtin_amdgcn_exp2f(x)
#endif
#endif
#ifndef EXP2
#define EXP2(x) exp2f(x)
#endif

__device__ __forceinline__ void async_cp16(const void* g, void* l) {
  __builtin_amdgcn_global_load_lds(
      (const __attribute__((address_space(1))) unsigned int*)g,
      (__attribute__((address_space(3))) unsigned int*)l, 16, 0, 0);
}

__device__ __forceinline__ unsigned short f2bf_bits(float f) {
  bf16 b = __float2bfloat16(f);
  return *(unsigned short*)&b;
}

__device__ __forceinline__ float bfu2f(short u) {
  union { uint32_t i; float f; } c;
  c.i = ((uint32_t)(unsigned short)u) << 16;
  return c.f;
}

// ---------------- x cast: fp32 -> bf16, 4 elems/thread ----------------
__global__ void cast_to_bf16(const float* __restrict__ src, bf16* __restrict__ dst) {
  int i = blockIdx.x * 256 + threadIdx.x;   // grid sized exactly: n/4 threads
  float4 v = ((const float4*)src)[i];
  ushort4 o;
  o.x = f2bf_bits(v.x); o.y = f2bf_bits(v.y);
  o.z = f2bf_bits(v.z); o.w = f2bf_bits(v.w);
  ((ushort4*)dst)[i] = o;
}

// ---------------- weight transpose+cast: src[K][N] fp32 -> dst[N][K] bf16 ----
__global__ void transpose_cast(const float* __restrict__ src, bf16* __restrict__ dst,
                               int K, int N) {
  int idx = blockIdx.x * 256 + threadIdx.x;
  if (idx >= K * N) return;
  int k = idx / N, n = idx - k * N;
  dst[n * K + k] = __float2bfloat16(src[idx]);
}

// ------- bias precompute (bf16, per-kk contiguous): biasb[h][q 208][r2 224] ---
// r2 = kk*32 + quad*8 + i; maps to k = kk*32 + quad*8 + (i>=4?4:0) + (i&3)
// (the pi-permuted position matching the swapped-QK register layout, so each
//  lane reads ONE bf16x8 per kk). Pre-multiplied by log2(e).
// k >= 196: -1e30 (exp2 -> 0 masks those columns; K pad rows need no zeroing).
__global__ void bias_fill(const float* __restrict__ table, const int* __restrict__ rel,
                          bf16* __restrict__ biasb) {
  int idx = blockIdx.x * 256 + threadIdx.x;  // 12*208*224 = 559104 exact
  int h = idx / (QP * KPAD);
  int rem = idx - h * (QP * KPAD);
  int q = rem / KPAD, r2 = rem - q * KPAD;
  int kk = r2 >> 5, quad = (r2 >> 3) & 3, i = r2 & 7;
  int k = kk * 32 + quad * 8 + ((i >= 4) ? 4 : 0) + (i & 3);
  float v;
  if (q >= L_TOK)      v = 0.f;
  else if (k >= L_TOK) v = -1e30f;
  else                 v = table[rel[q * L_TOK + k] * NH + h] * 1.4426950408889634f;
  biasb[idx] = __float2bfloat16(v);
}

__device__ __forceinline__ void storev(bf16* p, float v)  { *p = __float2bfloat16(v); }
__device__ __forceinline__ void storev(float* p, float v) { *p = v; }

// ------- GEMM: C[M,N] = A[M,K](lda) @ Bt[N,K]^T + bias, C row-stride = N -------
// 1-D grid with M-panel swizzle; 2-phase double-buffered staging.
template <typename OT>
__global__ __launch_bounds__(256) void gemm_bt(
    const bf16* __restrict__ A, const bf16* __restrict__ Bt,
    const float* __restrict__ bias, OT* __restrict__ C,
    int M, int N, int K, int lda, int qcols, int nbn, int panel) {
  __shared__ __align__(16) bf16 sA[2][128 * 32];
  __shared__ __align__(16) bf16 sB[2][128 * 32];
  const int tid = threadIdx.x;
  const int wave = tid >> 6, lane = tid & 63;
  const int SUPER = panel * nbn;
  const int bid = blockIdx.x;
  const int sb = bid / SUPER, rsp = bid - sb * SUPER;
  const long bm = (long)(sb * panel + rsp % panel) * 128;
  const long bn = (long)(rsp / panel) * 128;

  const int srow = wave * 32 + (lane >> 2);
  const int scol = (lane & 3) * 8;
  const bf16* gA = A + (bm + srow) * (long)lda + scol;
  const bf16* gB = Bt + (bn + srow) * (long)K + scol;

  floatx4 acc[4][4];
#pragma unroll
  for (int i = 0; i < 4; i++)
#pragma unroll
    for (int j = 0; j < 4; j++) acc[i][j] = (floatx4)(0.f);

  const int wr = (wave & 1) * 64;
  const int wc = (wave >> 1) * 64;

#pragma unroll
  for (int j = 0; j < 2; j++) {
    async_cp16(gA + (size_t)j * 16 * lda, &sA[0][(wave * 32 + j * 16) * 32]);
    async_cp16(gB + (size_t)j * 16 * K, &sB[0][(wave * 32 + j * 16) * 32]);
  }
  __syncthreads();

  int cur = 0;
  for (int k0 = 0; k0 < K; k0 += 32) {
    if (k0 + 32 < K) {
#pragma unroll
      for (int j = 0; j < 2; j++) {
        async_cp16(gA + (size_t)j * 16 * lda + (k0 + 32),
                   &sA[cur ^ 1][(wave * 32 + j * 16) * 32]);
        async_cp16(gB + (size_t)j * 16 * K + (k0 + 32),
                   &sB[cur ^ 1][(wave * 32 + j * 16) * 32]);
      }
    }
    frag8 af[4], bfr[4];
#pragma unroll
    for (int mi = 0; mi < 4; mi++)
      af[mi] = *(const frag8*)&sA[cur][(wr + mi * 16 + (lane & 15)) * 32 + (lane >> 4) * 8];
#pragma unroll
    for (int ni = 0; ni < 4; ni++)
      bfr[ni] = *(const frag8*)&sB[cur][(wc + ni * 16 + (lane & 15)) * 32 + (lane >> 4) * 8];
#pragma unroll
    for (int mi = 0; mi < 4; mi++)
#pragma unroll
      for (int ni = 0; ni < 4; ni++)
        acc[mi][ni] = __builtin_amdgcn_mfma_f32_16x16x32_bf16(af[mi], bfr[ni], acc[mi][ni], 0, 0, 0);
    __syncthreads();
    cur ^= 1;
  }

#pragma unroll
  for (int ni = 0; ni < 4; ni++) {
    const long col = bn + wc + ni * 16 + (lane & 15);
    const float bv = bias[col];
#pragma unroll
    for (int mi = 0; mi < 4; mi++)
#pragma unroll
      for (int r = 0; r < 4; r++) {
        const long row = bm + wr + mi * 16 + (lane >> 4) * 4 + r;
        float val = acc[mi][ni][r] + bv;
        if (col < qcols) val *= QSCALE;
        storev(&C[row * N + col], val);
      }
  }
}

// ---------------- fused window attention (v6: 8-wave, <=64 VGPR) -------------
// 512 threads = 8 waves; each wave owns rg = {wave, wave+8}. launch_bounds
// (512,8) forces VGPR<=64 -> 8 waves/SIMD = 32 waves/CU (the 64-reg cliff).
// QK and PV interleaved per kk-chunk: ap[7] (28 VGPR) -> one transient ap (4);
// bias is bf16, per-kk-contiguous, 3-deep rotating prefetch (12 VGPR).
__global__ __launch_bounds__(512, 8) void attn_win(
    bf16* __restrict__ qkv, const bf16* __restrict__ biasb) {
  __shared__ __align__(16) bf16 kL[KPAD * 32];     // 14336 B, linear 64B rows
  __shared__ __align__(16) bf16 vT[HD * VSTR];     // 15104 B  (total 29440 B)
  const int b = blockIdx.x, h = blockIdx.y;
  const int tid = threadIdx.x, wave = tid >> 6, lane = tid & 63;
  bf16* base = qkv + (size_t)b * L_TOK * (3 * C_DIM);

  const int colb = lane & 15;
  const int quad = lane >> 4;
  const int rsub = quad * 4;
  const int kswz = (quad ^ ((colb >> 1) & 3)) * 8;   // slot-XOR for kL reads

  // ---- V gather: issue global loads first (oldest in vmem queue) ----
  const bf16* vbase = base + 2 * C_DIM + h * HD;
  const int r0a = tid >> 2, c8a = (tid & 3) * 8;
  const bool hv = tid < 392;
  uint4 a0 = make_uint4(0, 0, 0, 0), a1 = make_uint4(0, 0, 0, 0);
  if (hv) {
    const bf16* ga = vbase + (size_t)(2 * r0a) * (3 * C_DIM) + c8a;
    a0 = *(const uint4*)ga;
    a1 = *(const uint4*)(ga + 3 * C_DIM);
  }

  // ---- K: async global->LDS, 14 chunks of 1024B over 8 waves ----
  for (int c = wave; c < 14; c += 8) {
    const int j = c * 16 + (lane >> 2);
    const int slot = lane & 3;
    const int t = j >> 4, qd = (j >> 2) & 3, rr = j & 3;
    int k = (t >> 1) * 32 + qd * 8 + (t & 1) * 4 + rr;
    if (k > L_TOK - 1) k = L_TOK - 1;       // clamp: bias -1e30 masks these cols
    const int sj = (j >> 1) & 3;
    const bf16* src = base + (size_t)k * (3 * C_DIM) + C_DIM + h * HD + ((slot ^ sj) * 8);
    async_cp16(src, &kL[c * 512]);
  }

  // ---- Q prefetch for both rg iterations ----
  frag8 aq0, aq1;
  {
    int q0 = wave * 16 + colb;                       // <= 127, no clamp needed
    aq0 = *(const frag8*)(base + (size_t)q0 * (3 * C_DIM) + h * HD + quad * 8);
    int rg1 = wave + 8; if (rg1 > 12) rg1 = 12;
    int q1 = rg1 * 16 + colb; if (q1 > L_TOK - 1) q1 = L_TOK - 1;
    aq1 = *(const frag8*)(base + (size_t)q1 * (3 * C_DIM) + h * HD + quad * 8);
  }

  // ---- first-rg bias prefetch (3-deep) issued pre-barrier ----
  const bf16* biasB = biasb + (size_t)h * QP * KPAD;
  const bf16* bRow0 = biasB + (size_t)(wave * 16 + colb) * KPAD;
  frag8 p00 = *(const frag8*)&bRow0[0 * 32 + quad * 8];
  frag8 p01 = *(const frag8*)&bRow0[1 * 32 + quad * 8];
  frag8 p02 = *(const frag8*)&bRow0[2 * 32 + quad * 8];

  // ---- V transpose writes ----
  if (hv) {
    ushort ea0[8], ea1[8];
    *(uint4*)ea0 = a0; *(uint4*)ea1 = a1;
#pragma unroll
    for (int e = 0; e < 8; e++) {
      uint32_t pack = (uint32_t)ea0[e] | ((uint32_t)ea1[e] << 16);
      *(uint32_t*)&vT[(c8a + e) * VSTR + 2 * r0a] = pack;
    }
  }
  // zero V pad rows [196,224)
  if (tid < HD * 14) {
    int d = tid / 14, pr = tid - d * 14;
    *(uint32_t*)&vT[d * VSTR + L_TOK + 2 * pr] = 0;
  }
  __syncthreads();

  // ---- per-rg body: QK/PV interleaved per kk; bias rotating prefetch ----
  auto rg_body = [&](int rg, frag8 aq, const bf16* bRow,
                     frag8 b0, frag8 b1, frag8 b2) {
    const int row0 = rg * 16;
    frag8 bb[7];
    bb[0] = b0; bb[1] = b1; bb[2] = b2;
    floatx4 o0 = (floatx4)(0.f), o1 = (floatx4)(0.f);
    float lsum = 0.f;
#pragma unroll
    for (int kk = 0; kk < 7; kk++) {
      const frag8 k0 = *(const frag8*)&kL[((2 * kk) * 16 + colb) * 32 + kswz];
      const frag8 k1 = *(const frag8*)&kL[((2 * kk + 1) * 16 + colb) * 32 + kswz];
      floatx4 s0 = __builtin_amdgcn_mfma_f32_16x16x32_bf16(k0, aq, (floatx4)(0.f), 0, 0, 0);
      floatx4 s1 = __builtin_amdgcn_mfma_f32_16x16x32_bf16(k1, aq, (floatx4)(0.f), 0, 0, 0);
      if (kk + 3 < 7) bb[kk + 3] = *(const frag8*)&bRow[(kk + 3) * 32 + quad * 8];
      frag8 ap;
#pragma unroll
      for (int e = 0; e < 4; e++) {
        float p = EXP2(s0[e] + bfu2f(bb[kk][e]));
        lsum += p;
        ap[e] = (short)f2bf_bits(p);
      }
#pragma unroll
      for (int e = 0; e < 4; e++) {
        float p = EXP2(s1[e] + bfu2f(bb[kk][4 + e]));
        lsum += p;
        ap[4 + e] = (short)f2bf_bits(p);
      }
      const frag8 bv0 = *(const frag8*)&vT[colb * VSTR + kk * 32 + quad * 8];
      const frag8 bv1 = *(const frag8*)&vT[(16 + colb) * VSTR + kk * 32 + quad * 8];
      o0 = __builtin_amdgcn_mfma_f32_16x16x32_bf16(ap, bv0, o0, 0, 0, 0);
      o1 = __builtin_amdgcn_mfma_f32_16x16x32_bf16(ap, bv1, o1, 0, 0, 0);
    }
    lsum += __shfl_xor(lsum, 16, 64);
    lsum += __shfl_xor(lsum, 32, 64);
    const float rl = 1.0f / lsum;
#pragma unroll
    for (int r = 0; r < 4; r++) {
      const float rn = __shfl(rl, rsub + r, 64);
      const int grow = row0 + rsub + r;
      if (grow < L_TOK) {
        base[(size_t)grow * (3 * C_DIM) + h * HD + colb] = __float2bfloat16(o0[r] * rn);
        base[(size_t)grow * (3 * C_DIM) + h * HD + 16 + colb] = __float2bfloat16(o1[r] * rn);
      }
    }
  };

  rg_body(wave, aq0, bRow0, p00, p01, p02);
  if (wave < 5) {
    const int rg1 = wave + 8;
    const bf16* bRow1 = biasB + (size_t)(rg1 * 16 + colb) * KPAD;
    frag8 q0 = *(const frag8*)&bRow1[0 * 32 + quad * 8];
    frag8 q1 = *(const frag8*)&bRow1[1 * 32 + quad * 8];
    frag8 q2 = *(const frag8*)&bRow1[2 * 32 + quad * 8];
    rg_body(rg1, aq1, bRow1, q0, q1, q2);
  }
}

extern "C" void kernel_launch(void* const* d_in, const int* in_sizes, int n_in,
                              void* d_out, int out_size, void* d_ws, size_t ws_size,
                              hipStream_t stream) {
  const float* x      = (const float*)d_in[0];
  const float* qkv_w  = (const float*)d_in[1];
  const float* qkv_b  = (const float*)d_in[2];
  const float* proj_w = (const float*)d_in[3];
  const float* proj_b = (const float*)d_in[4];
  const float* btab   = (const float*)d_in[5];
  const int*   relidx = (const int*)d_in[6];
  float* out = (float*)d_out;

  const size_t M = (size_t)B_WIN * L_TOK;  // 100352
  char* ws = (char*)d_ws;
  size_t off = 0;
  bf16*  qkv   = (bf16*)(ws + off);  off += M * 1152 * 2;              // 231.2 MB
  bf16*  wT1   = (bf16*)(ws + off);  off += (size_t)1152 * 384 * 2;    // 0.88 MB
  bf16*  wT2   = (bf16*)(ws + off);  off += (size_t)384 * 384 * 2;     // 0.29 MB
  bf16*  biasb = (bf16*)(ws + off);  off += (size_t)NH * QP * KPAD * 2;// 1.12 MB

  // x cast to bf16: prefer workspace; fall back to d_out aliasing.
  bf16* xb = (ws_size >= off + M * C_DIM * sizeof(bf16))
                 ? (bf16*)(ws + off) : (bf16*)d_out;

  cast_to_bf16<<<(int)(M * C_DIM / 4 / 256), 256, 0, stream>>>(x, xb);
  transpose_cast<<<(384 * 1152 + 255) / 256, 256, 0, stream>>>(qkv_w, wT1, 384, 1152);
  transpose_cast<<<(384 * 384 + 255) / 256, 256, 0, stream>>>(proj_w, wT2, 384, 384);
  bias_fill<<<(NH * QP * KPAD) / 256, 256, 0, stream>>>(btab, relidx, biasb);

  gemm_bt<bf16><<<784 * 9, 256, 0, stream>>>(xb, wT1, qkv_b, qkv,
                                             (int)M, 1152, 384, 384, C_DIM, 9, 28);
  attn_win<<<dim3(B_WIN, NH), 512, 0, stream>>>(qkv, biasb);
  gemm_bt<float><<<784 * 3, 256, 0, stream>>>(qkv, wT2, proj_b, out,
                                              (int)M, 384, 384, 1152, 0, 3, 28);
}

// Round 5
// 602.389 us; speedup vs baseline: 1.7421x; 1.7421x over previous
//
#include <hip/hip_runtime.h>
#include <hip/hip_bf16.h>
#include <stdint.h>

typedef __hip_bfloat16 bf16;
typedef __attribute__((ext_vector_type(8))) short frag8;     // 8 bf16 = 4 VGPRs
typedef __attribute__((ext_vector_type(4))) float floatx4;   // MFMA acc

#define B_WIN 512
#define L_TOK 196
#define C_DIM 384
#define NH    12
#define HD    32
#define QP    208   // 13*16 q-rows padded
#define KPAD  224   // 14*16 k padded (exactly 56 P-vals/lane = 7 PV chunks)
#define VSTR  236   // vT row stride: 472B. write: 2-way; read: free
// scale = hd^-0.5 * log2(e)  (exp2 softmax; base change folded into logits+bias)
#define QSCALE 0.2550348555f

#if defined(__has_builtin)
#if __has_builtin(__builtin_amdgcn_exp2f)
#define EXP2(x) __builtin_amdgcn_exp2f(x)
#endif
#endif
#ifndef EXP2
#define EXP2(x) exp2f(x)
#endif

__device__ __forceinline__ void async_cp16(const void* g, void* l) {
  __builtin_amdgcn_global_load_lds(
      (const __attribute__((address_space(1))) unsigned int*)g,
      (__attribute__((address_space(3))) unsigned int*)l, 16, 0, 0);
}

__device__ __forceinline__ unsigned short f2bf_bits(float f) {
  bf16 b = __float2bfloat16(f);
  return *(unsigned short*)&b;
}

__device__ __forceinline__ float bfu2f(short u) {
  union { uint32_t i; float f; } c;
  c.i = ((uint32_t)(unsigned short)u) << 16;
  return c.f;
}

// ---------------- x cast: fp32 -> bf16, 4 elems/thread ----------------
__global__ void cast_to_bf16(const float* __restrict__ src, bf16* __restrict__ dst) {
  int i = blockIdx.x * 256 + threadIdx.x;   // grid sized exactly: n/4 threads
  float4 v = ((const float4*)src)[i];
  ushort4 o;
  o.x = f2bf_bits(v.x); o.y = f2bf_bits(v.y);
  o.z = f2bf_bits(v.z); o.w = f2bf_bits(v.w);
  ((ushort4*)dst)[i] = o;
}

// ---------------- weight transpose+cast: src[K][N] fp32 -> dst[N][K] bf16 ----
__global__ void transpose_cast(const float* __restrict__ src, bf16* __restrict__ dst,
                               int K, int N) {
  int idx = blockIdx.x * 256 + threadIdx.x;
  if (idx >= K * N) return;
  int k = idx / N, n = idx - k * N;
  dst[n * K + k] = __float2bfloat16(src[idx]);
}

// ------- bias precompute (bf16, per-kk contiguous): biasb[h][q 208][r2 224] ---
// r2 = kk*32 + quad*8 + i; maps to k = kk*32 + quad*8 + (i>=4?4:0) + (i&3)
// (the pi-permuted position matching the swapped-QK register layout, so each
//  lane reads ONE bf16x8 per kk). Pre-multiplied by log2(e).
// k >= 196: -1e30 (exp2 -> 0 masks those columns; K pad rows need no zeroing).
__global__ void bias_fill(const float* __restrict__ table, const int* __restrict__ rel,
                          bf16* __restrict__ biasb) {
  int idx = blockIdx.x * 256 + threadIdx.x;  // 12*208*224 = 559104 exact
  int h = idx / (QP * KPAD);
  int rem = idx - h * (QP * KPAD);
  int q = rem / KPAD, r2 = rem - q * KPAD;
  int kk = r2 >> 5, quad = (r2 >> 3) & 3, i = r2 & 7;
  int k = kk * 32 + quad * 8 + ((i >= 4) ? 4 : 0) + (i & 3);
  float v;
  if (q >= L_TOK)      v = 0.f;
  else if (k >= L_TOK) v = -1e30f;
  else                 v = table[rel[q * L_TOK + k] * NH + h] * 1.4426950408889634f;
  biasb[idx] = __float2bfloat16(v);
}

__device__ __forceinline__ void storev(bf16* p, float v)  { *p = __float2bfloat16(v); }
__device__ __forceinline__ void storev(float* p, float v) { *p = v; }

// ------- GEMM: C[M,N] = A[M,K](lda) @ Bt[N,K]^T + bias, C row-stride = N -------
// 3-buffer, 2-ahead pipeline with COUNTED vmcnt (T3/T4): issue stage t+2,
// compute on buf t, then s_waitcnt vmcnt(4) (stage t+1 landed, t+2 still in
// flight) + raw s_barrier. vmcnt never drains to 0 in the steady loop; each
// wave issues exactly 4 global_load_lds per stage so the count is exact.
// Race-safety: ds_reads of buf t are register-complete (lgkmcnt) before the
// MFMAs that precede the barrier; buf t is only overwritten by stage t+3,
// issued after the NEXT barrier.
template <typename OT>
__global__ __launch_bounds__(256) void gemm_bt(
    const bf16* __restrict__ A, const bf16* __restrict__ Bt,
    const float* __restrict__ bias, OT* __restrict__ C,
    int M, int N, int K, int lda, int qcols, int nbn, int panel) {
  __shared__ __align__(16) bf16 sA[3][128 * 32];
  __shared__ __align__(16) bf16 sB[3][128 * 32];
  const int tid = threadIdx.x;
  const int wave = tid >> 6, lane = tid & 63;
  const int SUPER = panel * nbn;
  const int bid = blockIdx.x;
  const int sb = bid / SUPER, rsp = bid - sb * SUPER;
  const long bm = (long)(sb * panel + rsp % panel) * 128;
  const long bn = (long)(rsp / panel) * 128;

  const int srow = wave * 32 + (lane >> 2);
  const int scol = (lane & 3) * 8;
  const bf16* gA = A + (bm + srow) * (long)lda + scol;
  const bf16* gB = Bt + (bn + srow) * (long)K + scol;

  floatx4 acc[4][4];
#pragma unroll
  for (int i = 0; i < 4; i++)
#pragma unroll
    for (int j = 0; j < 4; j++) acc[i][j] = (floatx4)(0.f);

  const int wr = (wave & 1) * 64;
  const int wc = (wave >> 1) * 64;
  const int nst = K >> 5;   // k-steps of 32 (384 -> 12)

#define STAGE(s, buf)                                                        \
  do {                                                                       \
    _Pragma("unroll")                                                        \
    for (int j = 0; j < 2; j++) {                                            \
      async_cp16(gA + (size_t)j * 16 * lda + (s) * 32,                       \
                 &sA[buf][(wave * 32 + j * 16) * 32]);                       \
      async_cp16(gB + (size_t)j * 16 * K + (s) * 32,                         \
                 &sB[buf][(wave * 32 + j * 16) * 32]);                       \
    }                                                                        \
  } while (0)

  STAGE(0, 0);
  STAGE(1, 1);
  asm volatile("s_waitcnt vmcnt(4)" ::: "memory");   // stage 0 landed
  __builtin_amdgcn_s_barrier();

  int cur = 0;
  for (int t = 0; t < nst; ++t) {
    if (t + 2 < nst) {
      int nb = cur + 2; if (nb >= 3) nb -= 3;
      STAGE(t + 2, nb);
    }
    frag8 af[4], bfr[4];
#pragma unroll
    for (int mi = 0; mi < 4; mi++)
      af[mi] = *(const frag8*)&sA[cur][(wr + mi * 16 + (lane & 15)) * 32 + (lane >> 4) * 8];
#pragma unroll
    for (int ni = 0; ni < 4; ni++)
      bfr[ni] = *(const frag8*)&sB[cur][(wc + ni * 16 + (lane & 15)) * 32 + (lane >> 4) * 8];
#pragma unroll
    for (int mi = 0; mi < 4; mi++)
#pragma unroll
      for (int ni = 0; ni < 4; ni++)
        acc[mi][ni] = __builtin_amdgcn_mfma_f32_16x16x32_bf16(af[mi], bfr[ni], acc[mi][ni], 0, 0, 0);
    if (t + 1 < nst) {
      if (t + 2 < nst) asm volatile("s_waitcnt vmcnt(4)" ::: "memory"); // t+1 landed
      else             asm volatile("s_waitcnt vmcnt(0)" ::: "memory"); // tail drain
      __builtin_amdgcn_s_barrier();
    }
    cur = (cur == 2) ? 0 : cur + 1;
  }
#undef STAGE

#pragma unroll
  for (int ni = 0; ni < 4; ni++) {
    const long col = bn + wc + ni * 16 + (lane & 15);
    const float bv = bias[col];
#pragma unroll
    for (int mi = 0; mi < 4; mi++)
#pragma unroll
      for (int r = 0; r < 4; r++) {
        const long row = bm + wr + mi * 16 + (lane >> 4) * 4 + r;
        float val = acc[mi][ni][r] + bv;
        if (col < qcols) val *= QSCALE;
        storev(&C[row * N + col], val);
      }
  }
}

// ---------------- fused window attention (v7: v5/v6 hybrid, no forced cap) ---
// 256 threads / 4 waves, NO min-waves clause (r2/r4 lesson: forcing spills).
// Register diet instead: QK/PV interleaved per kk (transient ap, 4 VGPR),
// bf16 bias one frag8 per kk, Q loaded JIT per rg. Target: land <=64 VGPR
// naturally -> 8 waves/SIMD cap, LDS caps at 5 blocks/CU (20 waves).
__global__ __launch_bounds__(256) void attn_win(
    bf16* __restrict__ qkv, const bf16* __restrict__ biasb) {
  __shared__ __align__(16) bf16 kL[KPAD * 32];     // 14336 B, linear 64B rows
  __shared__ __align__(16) bf16 vT[HD * VSTR];     // 15104 B  (total 29440 B)
  const int b = blockIdx.x, h = blockIdx.y;
  const int tid = threadIdx.x, wave = tid >> 6, lane = tid & 63;
  bf16* base = qkv + (size_t)b * L_TOK * (3 * C_DIM);

  const int colb = lane & 15;
  const int quad = lane >> 4;
  const int rsub = quad * 4;
  const int kswz = (quad ^ ((colb >> 1) & 3)) * 8;   // slot-XOR for kL reads

  // ---- V gather: issue ALL global loads first (oldest in vmem queue) ----
  const bf16* vbase = base + 2 * C_DIM + h * HD;
  const int r0a = tid >> 2, c8a = (tid & 3) * 8;
  const bf16* ga = vbase + (size_t)(2 * r0a) * (3 * C_DIM) + c8a;
  uint4 a0 = *(const uint4*)ga;
  uint4 a1 = *(const uint4*)(ga + 3 * C_DIM);
  const int i1 = tid + 256;
  const bool h1 = i1 < 392;
  const int r0b = h1 ? (i1 >> 2) : r0a, c8b = h1 ? (i1 & 3) * 8 : c8a;
  const bf16* gb = vbase + (size_t)(2 * r0b) * (3 * C_DIM) + c8b;
  uint4 b0 = make_uint4(0, 0, 0, 0), b1 = make_uint4(0, 0, 0, 0);
  if (h1) { b0 = *(const uint4*)gb; b1 = *(const uint4*)(gb + 3 * C_DIM); }

  // ---- K: async global->LDS, 14 chunks of 1024B (rows j = c*16..c*16+15).
  // LDS is linear; the slot permutation is applied on the global source:
  // LDS slot w of row j holds K[pi(j)] quad (w ^ ((j>>1)&3)).
  for (int c = wave; c < 14; c += 4) {
    const int j = c * 16 + (lane >> 2);
    const int slot = lane & 3;
    const int t = j >> 4, qd = (j >> 2) & 3, rr = j & 3;
    int k = (t >> 1) * 32 + qd * 8 + (t & 1) * 4 + rr;
    if (k > L_TOK - 1) k = L_TOK - 1;       // clamp: bias -1e30 masks these cols
    const int sj = (j >> 1) & 3;
    const bf16* src = base + (size_t)k * (3 * C_DIM) + C_DIM + h * HD + ((slot ^ sj) * 8);
    async_cp16(src, &kL[c * 512]);
  }

  // ---- V transpose writes (vmcnt wait covers only the V loads) ----
  {
    ushort ea0[8], ea1[8];
    *(uint4*)ea0 = a0; *(uint4*)ea1 = a1;
#pragma unroll
    for (int e = 0; e < 8; e++) {
      uint32_t pack = (uint32_t)ea0[e] | ((uint32_t)ea1[e] << 16);
      *(uint32_t*)&vT[(c8a + e) * VSTR + 2 * r0a] = pack;
    }
    if (h1) {
      ushort eb0[8], eb1[8];
      *(uint4*)eb0 = b0; *(uint4*)eb1 = b1;
#pragma unroll
      for (int e = 0; e < 8; e++) {
        uint32_t pack = (uint32_t)eb0[e] | ((uint32_t)eb1[e] << 16);
        *(uint32_t*)&vT[(c8b + e) * VSTR + 2 * r0b] = pack;
      }
    }
  }
  // zero V pad rows [196,224) (P there is exactly 0, but LDS garbage could be NaN)
  for (int idx = tid; idx < HD * 14; idx += 256) {
    int d = idx / 14, pr = idx - d * 14;
    *(uint32_t*)&vT[d * VSTR + L_TOK + 2 * pr] = 0;
  }
  __syncthreads();

  const bf16* biasB = biasb + (size_t)h * QP * KPAD;

#pragma unroll
  for (int ii = 0; ii < 4; ii++) {
    const int rg = wave + 4 * ii;
    if (rg < 13) {
      const int row0 = rg * 16;
      int qrow = row0 + colb; if (qrow > L_TOK - 1) qrow = L_TOK - 1;
      const frag8 aq = *(const frag8*)(base + (size_t)qrow * (3 * C_DIM) + h * HD + quad * 8);
      const bf16* bRow = biasB + (size_t)(row0 + colb) * KPAD;

      floatx4 o0 = (floatx4)(0.f), o1 = (floatx4)(0.f);
      float lsum = 0.f;
#pragma unroll
      for (int kk = 0; kk < 7; kk++) {
        const frag8 k0 = *(const frag8*)&kL[((2 * kk) * 16 + colb) * 32 + kswz];
        const frag8 k1 = *(const frag8*)&kL[((2 * kk + 1) * 16 + colb) * 32 + kswz];
        floatx4 s0 = __builtin_amdgcn_mfma_f32_16x16x32_bf16(k0, aq, (floatx4)(0.f), 0, 0, 0);
        floatx4 s1 = __builtin_amdgcn_mfma_f32_16x16x32_bf16(k1, aq, (floatx4)(0.f), 0, 0, 0);
        const frag8 bb = *(const frag8*)&bRow[kk * 32 + quad * 8];
        frag8 ap;
#pragma unroll
        for (int e = 0; e < 4; e++) {
          float p = EXP2(s0[e] + bfu2f(bb[e]));
          lsum += p;
          ap[e] = (short)f2bf_bits(p);
        }
#pragma unroll
        for (int e = 0; e < 4; e++) {
          float p = EXP2(s1[e] + bfu2f(bb[4 + e]));
          lsum += p;
          ap[4 + e] = (short)f2bf_bits(p);
        }
        const frag8 bv0 = *(const frag8*)&vT[colb * VSTR + kk * 32 + quad * 8];
        const frag8 bv1 = *(const frag8*)&vT[(16 + colb) * VSTR + kk * 32 + quad * 8];
        o0 = __builtin_amdgcn_mfma_f32_16x16x32_bf16(ap, bv0, o0, 0, 0, 0);
        o1 = __builtin_amdgcn_mfma_f32_16x16x32_bf16(ap, bv1, o1, 0, 0, 0);
      }
      lsum += __shfl_xor(lsum, 16, 64);
      lsum += __shfl_xor(lsum, 32, 64);
      const float rl = 1.0f / lsum;
#pragma unroll
      for (int r = 0; r < 4; r++) {
        const float rn = __shfl(rl, rsub + r, 64);
        const int grow = row0 + rsub + r;
        if (grow < L_TOK) {
          base[(size_t)grow * (3 * C_DIM) + h * HD + colb] = __float2bfloat16(o0[r] * rn);
          base[(size_t)grow * (3 * C_DIM) + h * HD + 16 + colb] = __float2bfloat16(o1[r] * rn);
        }
      }
    }
  }
}

extern "C" void kernel_launch(void* const* d_in, const int* in_sizes, int n_in,
                              void* d_out, int out_size, void* d_ws, size_t ws_size,
                              hipStream_t stream) {
  const float* x      = (const float*)d_in[0];
  const float* qkv_w  = (const float*)d_in[1];
  const float* qkv_b  = (const float*)d_in[2];
  const float* proj_w = (const float*)d_in[3];
  const float* proj_b = (const float*)d_in[4];
  const float* btab   = (const float*)d_in[5];
  const int*   relidx = (const int*)d_in[6];
  float* out = (float*)d_out;

  const size_t M = (size_t)B_WIN * L_TOK;  // 100352
  char* ws = (char*)d_ws;
  size_t off = 0;
  bf16*  qkv   = (bf16*)(ws + off);  off += M * 1152 * 2;              // 231.2 MB
  bf16*  wT1   = (bf16*)(ws + off);  off += (size_t)1152 * 384 * 2;    // 0.88 MB
  bf16*  wT2   = (bf16*)(ws + off);  off += (size_t)384 * 384 * 2;     // 0.29 MB
  bf16*  biasb = (bf16*)(ws + off);  off += (size_t)NH * QP * KPAD * 2;// 1.12 MB

  // x cast to bf16: prefer workspace; fall back to d_out aliasing.
  bf16* xb = (ws_size >= off + M * C_DIM * sizeof(bf16))
                 ? (bf16*)(ws + off) : (bf16*)d_out;

  cast_to_bf16<<<(int)(M * C_DIM / 4 / 256), 256, 0, stream>>>(x, xb);
  transpose_cast<<<(384 * 1152 + 255) / 256, 256, 0, stream>>>(qkv_w, wT1, 384, 1152);
  transpose_cast<<<(384 * 384 + 255) / 256, 256, 0, stream>>>(proj_w, wT2, 384, 384);
  bias_fill<<<(NH * QP * KPAD) / 256, 256, 0, stream>>>(btab, relidx, biasb);

  gemm_bt<bf16><<<784 * 9, 256, 0, stream>>>(xb, wT1, qkv_b, qkv,
                                             (int)M, 1152, 384, 384, C_DIM, 9, 28);
  attn_win<<<dim3(B_WIN, NH), 256, 0, stream>>>(qkv, biasb);
  gemm_bt<float><<<784 * 3, 256, 0, stream>>>(qkv, wT2, proj_b, out,
                                              (int)M, 384, 384, 1152, 0, 3, 28);
}